// Round 11
// baseline (219.124 us; speedup 1.0000x reference)
//
#include <hip/hip_runtime.h>
#include <hip/hip_bf16.h>
#include <cstdint>
#include <cstddef>

typedef __hip_bfloat16 bf16;
using short8 = __attribute__((ext_vector_type(8))) short;
using f32x4  = __attribute__((ext_vector_type(4))) float;

static constexpr int   kNC    = 1026;   // n_fft + 2 (real interleaved cols)
static constexpr float kTwoPi = 6.283185307179586f;

#define GLDS(g, l) __builtin_amdgcn_global_load_lds(                       \
    (const __attribute__((address_space(1))) uint32_t*)(g),                \
    (__attribute__((address_space(3))) uint32_t*)(l), 16, 0, 0)

#define BAR()   { __builtin_amdgcn_sched_barrier(0); __builtin_amdgcn_s_barrier(); \
                  asm volatile("" ::: "memory"); }
#define LGKM0() { asm volatile("s_waitcnt lgkmcnt(0)" ::: "memory"); __builtin_amdgcn_sched_barrier(0); }
#define VM6()   { asm volatile("s_waitcnt vmcnt(6)"   ::: "memory"); __builtin_amdgcn_sched_barrier(0); }
#define VM0()   { asm volatile("s_waitcnt vmcnt(0)"   ::: "memory"); __builtin_amdgcn_sched_barrier(0); }

static __device__ __forceinline__ float b2f(short u) {
    union { short s; bf16 h; } c; c.s = u; return __bfloat162float(c.h);
}

// ---------------------------------------------------------------- prep: x -> bf16
__global__ void cvt_x_k(const float* __restrict__ x, bf16* __restrict__ xb) {
    size_t i = ((size_t)blockIdx.x * 256 + threadIdx.x) * 8;
    float4 a = *(const float4*)(x + i);
    float4 c = *(const float4*)(x + i + 4);
    union { bf16 h[8]; uint4 u; } o;
    o.h[0] = __float2bfloat16(a.x); o.h[1] = __float2bfloat16(a.y);
    o.h[2] = __float2bfloat16(a.z); o.h[3] = __float2bfloat16(a.w);
    o.h[4] = __float2bfloat16(c.x); o.h[5] = __float2bfloat16(c.y);
    o.h[6] = __float2bfloat16(c.z); o.h[7] = __float2bfloat16(c.w);
    *(uint4*)(xb + i) = o.u;
}

// ------------------------------------------- prep: W -> Wr [1152][512] interleaved
__global__ void prep_w_k(const float* __restrict__ W, const float* __restrict__ b,
                         bf16* __restrict__ Wr, float* __restrict__ br) {
    int j = blockIdx.x;
    int col = -1;
    if (j < 1024)       col = (j & 1) ? 513 + (j >> 1) : (j >> 1);
    else if (j == 1024) col = 512;
    else if (j == 1025) col = 1025;
    for (int k = threadIdx.x; k < 512; k += 256) {
        float v = (col >= 0) ? W[(size_t)k * 1026 + col] : 0.0f;
        Wr[(size_t)j * 512 + k] = __float2bfloat16(v);
    }
    if (threadIdx.x == 0) br[j] = (col >= 0) ? b[col] : 0.0f;
}

// ------------------------- prep: Mc/Ms [640][512] cos/sin irfft half-matrices
__global__ void prep_mcs_k(bf16* __restrict__ Mc, bf16* __restrict__ Ms) {
    const int r = blockIdx.x;                     // output row n-bar (0..639)
    for (int kk = threadIdx.x; kk < 512; kk += 256) {
        float vc = 0.0f, vs = 0.0f;
        if (r <= 512) {
            int mm = (kk * r) & 1023;
            float ang = kTwoPi * (float)mm * (1.0f / 1024.0f);
            float alpha = (kk == 0) ? 1.0f : 2.0f;
            vc = alpha * (1.0f / 1024.0f) * cosf(ang);
            vs = alpha * (1.0f / 1024.0f) * sinf(ang);
        }
        Mc[(size_t)r * 512 + kk] = __float2bfloat16(vc);
        Ms[(size_t)r * 512 + kk] = __float2bfloat16(vs);
    }
}

// ------------------------------------------------------- prep: window tables
__global__ void prep_win_k(float* __restrict__ wg) {
    const int idx = blockIdx.x * 256 + threadIdx.x;   // 0..1023
    float wn = 0.5f - 0.5f * cosf(kTwoPi * (float)idx / 1023.0f);  // numpy hanning
    wg[idx] = wn;
    wg[1024 + idx] = wn * wn;
}

// --------------------- 256x128 triple-buffer single-barrier bf16 GEMM core (R8)
// LDS: 3 slabs x (A 32KB + B 16KB) = 144 KiB, XOR-swizzled 16B slots.
// EPI=1: Vocos epilogue (bias+exp/cos/sin), interleaved single-dest store (R8-exact).
// EPI=0: plain bf16 store. Both clip chunks to colg+8 <= LDO.
// A row stride LDA may differ from K (gemm2 reads 512-col panels of 1032-stride rows).
template<int K, int LDA, int LDO, int EPI>
__device__ __forceinline__
void gemm_impl(const bf16* __restrict__ A, const bf16* __restrict__ B,
               const float* __restrict__ bias, bf16* __restrict__ O,
               int row0, int col0)
{
    extern __shared__ __align__(16) bf16 lds[];   // 3 slabs x 24576 elems
    constexpr int NT = K / 64;

    const int tid  = threadIdx.x;
    const int w    = tid >> 6;
    const int lane = tid & 63;
    const int wr = w >> 1, wc = w & 1;            // wave grid 4(M) x 2(N)

    const int srow  = lane >> 3;
    const int sslot = (lane & 7) ^ srow;          // pre-swizzled global 16B slot

    const bf16* gA0 = A + (size_t)(row0 + srow) * LDA + sslot * 8;
    const bf16* gB0 = B + (size_t)(col0 + srow) * K + sslot * 8;

    auto stage = [&](int t, int s) {
        bf16* lA = lds + s * 24576;
        bf16* lB = lA + 16384;
        #pragma unroll
        for (int l = 0; l < 4; ++l) {
            const int c = w * 4 + l;
            GLDS(gA0 + (size_t)(8 * c) * LDA + (size_t)t * 64, lA + c * 512 + lane * 8);
        }
        #pragma unroll
        for (int l = 0; l < 2; ++l) {
            const int d = w * 2 + l;
            GLDS(gB0 + (size_t)(8 * d) * K + (size_t)t * 64, lB + d * 512 + lane * 8);
        }
    };

    short8 af[4][2], bq[4][2];
    auto ldregs = [&](int s) {
        const bf16* lA = lds + s * 24576;
        const bf16* lB = lA + 16384;
        #pragma unroll
        for (int fm = 0; fm < 4; ++fm)
            #pragma unroll
            for (int ks = 0; ks < 2; ++ks) {
                const int r  = wr * 64 + fm * 16 + (lane & 15);
                const int sl = (ks * 4 + (lane >> 4)) ^ (r & 7);
                af[fm][ks] = *(const short8*)(lA + r * 64 + sl * 8);
            }
        #pragma unroll
        for (int fn = 0; fn < 4; ++fn)
            #pragma unroll
            for (int ks = 0; ks < 2; ++ks) {
                const int r  = wc * 64 + fn * 16 + (lane & 15);
                const int sl = (ks * 4 + (lane >> 4)) ^ (r & 7);
                bq[fn][ks] = *(const short8*)(lB + r * 64 + sl * 8);
            }
    };

    f32x4 acc[4][4] = {};

    stage(0, 0);
    stage(1, 1);
    VM6();
    BAR();

    for (int t = 0; t < NT; ++t) {
        const int tp = (t + 2 < NT) ? t + 2 : NT - 1;   // clamped prefetch
        ldregs(t % 3);
        stage(tp, (t + 2) % 3);
        VM6();                                    // retire stage(t+1)
        LGKM0();                                  // own reads of slab t%3 done
        BAR();
        __builtin_amdgcn_s_setprio(1);
        #pragma unroll
        for (int ks = 0; ks < 2; ++ks)
            #pragma unroll
            for (int fm = 0; fm < 4; ++fm)
                #pragma unroll
                for (int fn = 0; fn < 4; ++fn)
                    acc[fm][fn] = __builtin_amdgcn_mfma_f32_16x16x32_bf16(
                        af[fm][ks], bq[fn][ks], acc[fm][fn], 0, 0, 0);
        __builtin_amdgcn_s_setprio(0);
    }
    VM0();
    BAR();                                        // LDS free for epilogue

    // epilogue: acc -> LDS (swizzled) -> coalesced store (R8-exact structure)
    char* eb = (char*)lds;                        // [256 rows][256 B]
    #pragma unroll
    for (int fm = 0; fm < 4; ++fm) {
        #pragma unroll
        for (int fn = 0; fn < 4; ++fn) {
            const int col = wc * 64 + fn * 16 + (lane & 15);     // 0..127 in tile
            const int n   = col0 + col;
            #pragma unroll
            for (int r = 0; r < 4; ++r) {
                const int row = wr * 64 + fm * 16 + (lane >> 4) * 4 + r;
                float v = acc[fm][fn][r];
                bf16 val;
                if constexpr (EPI == 1) {
                    v += bias[n];
                    float vo = __shfl_xor(v, 1);
                    float res = (n & 1) ? fminf(__expf(vo), 100.0f) * __sinf(v)
                                        : fminf(__expf(v), 100.0f) * __cosf(vo);
                    val = __float2bfloat16(n < kNC ? res : 0.0f);
                } else {
                    val = __float2bfloat16(v);
                }
                const int sw = (col >> 3) ^ (((row >> 2) & 7) << 1);
                *(bf16*)(eb + row * 256 + sw * 16 + (col & 7) * 2) = val;
            }
        }
    }
    asm volatile("s_waitcnt lgkmcnt(0)" ::: "memory");
    BAR();

    #pragma unroll
    for (int k2 = 0; k2 < 8; ++k2) {
        const int g   = tid + k2 * 512;           // 0..4095 16B-chunks
        const int row = g >> 4;
        const int s   = g & 15;
        const int sw  = s ^ (((row >> 2) & 7) << 1);
        short8 vv = *(const short8*)(eb + row * 256 + sw * 16);
        const int colg = col0 + s * 8;
        if (colg + 8 <= LDO)
            *(short8*)(O + (size_t)(row0 + row) * LDO + colg) = vv;
    }
}

// GEMM1: Sri[32768][1032] interleaved (R8-exact path); grid 1152 (mt128 x nt9)
__global__ __launch_bounds__(512, 2)
void gemm1_k(const bf16* __restrict__ A, const bf16* __restrict__ B,
             const float* __restrict__ bias, bf16* __restrict__ O) {
    const int nwg = gridDim.x, orig = blockIdx.x;
    const int bid = (orig & 7) * (nwg >> 3) + (orig >> 3);
    const int nt = bid % 9, mt = bid / 9;
    gemm_impl<512, 512, 1032, 1>(A, B, bias, O, mt * 256, nt * 128);
}

// ---------------- de-interleave in place: row slot [1032] -> [Re 0..511 | Im 0..511]
// plus R512[r] = Re_512 (col 1024). One row per block; LDS-buffered, no cross-block
// hazard (each block touches only its own row).
__global__ void deint_k(bf16* __restrict__ S, float* __restrict__ R512) {
    __shared__ uint32_t buf[513];
    const int r = blockIdx.x, tid = threadIdx.x;
    const uint32_t* src = (const uint32_t*)(S + (size_t)r * 1032);
    for (int i = tid; i < 513; i += 256) buf[i] = src[i];
    __syncthreads();
    bf16* dst = S + (size_t)r * 1032;
    for (int k = tid; k < 512; k += 256) {
        const uint32_t p = buf[k];
        union { unsigned short u; bf16 h; } lo, hi;
        lo.u = (unsigned short)(p & 0xFFFFu);
        hi.u = (unsigned short)(p >> 16);
        dst[k]       = lo.h;                      // Re_k
        dst[512 + k] = hi.h;                      // Im_k
    }
    if (tid == 0) {
        union { unsigned short u; bf16 h; } c;
        c.u = (unsigned short)(buf[512] & 0xFFFFu);
        R512[r] = __bfloat162float(c.h);
    }
}

// GEMM2: e = Sre@Mc^T, o = Sim@Ms^T, both [32768][520]; grid 1280 = 2 x (mt128 x nt5)
__global__ __launch_bounds__(512, 2)
void gemm2_k(const bf16* __restrict__ S, const bf16* __restrict__ Mc,
             const bf16* __restrict__ Ms, bf16* __restrict__ pe,
             bf16* __restrict__ po) {
    const int nwg = gridDim.x, orig = blockIdx.x;
    const int bid = (orig & 7) * (nwg >> 3) + (orig >> 3);
    const int eo = (bid >= 640) ? 1 : 0;
    const int b2 = bid - eo * 640;
    const int nt = b2 % 5, mt = b2 / 5;
    gemm_impl<512, 1032, 520, 0>(S + (eo ? 512 : 0), eo ? Ms : Mc, nullptr,
                                 eo ? po : pe, mt * 256, nt * 128);
}

// ------- overlap-add: frames[n] = (e[nbar] + (-1)^n R512/1024 -+ o[nbar]) * w[n]
__global__ void ola_k(const bf16* __restrict__ pe, const bf16* __restrict__ po,
                      const float* __restrict__ R512, const float* __restrict__ wg,
                      float* __restrict__ out) {
    __shared__ float w[1024], w2[1024];
    for (int i = threadIdx.x; i < 1024; i += 256) { w[i] = wg[i]; w2[i] = wg[1024 + i]; }
    __syncthreads();
    const int gid = blockIdx.x * 256 + threadIdx.x;
    const int o0  = gid * 8;
    const int bb  = o0 >> 19;
    const int oo  = o0 & 524287;
    const int s   = oo + 384;                     // multiple of 8
    const int tmax = s >> 8;
    float sum[8] = {}, env[8] = {};
    #pragma unroll
    for (int jj = 0; jj < 4; ++jj) {
        const int t = tmax - jj;
        if (t < 0 || t >= 2048) continue;
        const int n0 = s - (t << 8);              // [0,1016], multiple of 8
        const size_t rowi = (size_t)bb * 2048 + t;
        const size_t rb = rowi * 520;
        const float rc = R512[rowi] * (1.0f / 1024.0f);
        if (n0 <= 504) {                          // n = n0+e, parity = e&1
            short8 E  = *(const short8*)(pe + rb + n0);
            short8 Og = *(const short8*)(po + rb + n0);
            #pragma unroll
            for (int e = 0; e < 8; ++e) {
                float ev = b2f(E[e]) + ((e & 1) ? -rc : rc);
                sum[e] += (ev - b2f(Og[e])) * w[n0 + e];
                env[e] += w2[n0 + e];
            }
        } else {
            const int nb = 1024 - n0;             // [8,512], multiple of 8
            short8 Ea = *(const short8*)(pe + rb + nb - 8);
            short8 Eb = *(const short8*)(pe + rb + nb);
            short8 Oa = *(const short8*)(po + rb + nb - 8);
            short8 Ob = *(const short8*)(po + rb + nb);
            sum[0] += (b2f(Eb[0]) + rc + b2f(Ob[0])) * w[n0];
            env[0] += w2[n0];
            #pragma unroll
            for (int j = 1; j < 8; ++j) {
                float ev = b2f(Ea[8 - j]) + ((j & 1) ? -rc : rc);
                sum[j] += (ev + b2f(Oa[8 - j])) * w[n0 + j];
                env[j] += w2[n0 + j];
            }
        }
    }
    float4 r0, r1;
    r0.x = sum[0] / (env[0] + 1e-11f); r0.y = sum[1] / (env[1] + 1e-11f);
    r0.z = sum[2] / (env[2] + 1e-11f); r0.w = sum[3] / (env[3] + 1e-11f);
    r1.x = sum[4] / (env[4] + 1e-11f); r1.y = sum[5] / (env[5] + 1e-11f);
    r1.z = sum[6] / (env[6] + 1e-11f); r1.w = sum[7] / (env[7] + 1e-11f);
    *(float4*)(out + o0)     = r0;
    *(float4*)(out + o0 + 4) = r1;
}

// ---------------------------------------------------------------------- launcher
// ws budget: 137,245,184 B total — below the R2-proven 140,648,960 B bound.
extern "C" void kernel_launch(void* const* d_in, const int* in_sizes, int n_in,
                              void* d_out, int out_size, void* d_ws, size_t ws_size,
                              hipStream_t stream)
{
    const float* x = (const float*)d_in[0];
    const float* W = (const float*)d_in[1];
    const float* b = (const float*)d_in[2];
    float* out = (float*)d_out;

    char* ws = (char*)d_ws;
    size_t off = 0;
    auto alloc = [&](size_t bytes) { char* p = ws + off; off += (bytes + 255) & ~255ull; return p; };

    bf16*  Mc   = (bf16*) alloc(640ull * 512 * 2);     //    655,360
    bf16*  Ms   = (bf16*) alloc(640ull * 512 * 2);     //    655,360
    float* wg   = (float*)alloc(2048 * 4);             //      8,192
    float* br   = (float*)alloc(1152 * 4);             //      4,608
    float* R512 = (float*)alloc(32768ull * 4);         //    131,072
    bf16*  Sri  = (bf16*) alloc(32768ull * 1032 * 2);  // 67,633,152 (interleaved -> deint in place)
    char*  regC = alloc(68157440ull);                  // 68,157,440 (aliased)
    bf16*  xb = (bf16*)regC;                           // phase 1 (GEMM1 input)
    bf16*  Wr = (bf16*)(regC + 33554432ull);           // phase 1 [1152][512]
    bf16*  pe = (bf16*)regC;                           // phase 2 e [32768][520]
    bf16*  po = (bf16*)(regC + 34078720ull);           // phase 2 o [32768][520]

    hipFuncSetAttribute(reinterpret_cast<const void*>(gemm1_k),
                        hipFuncAttributeMaxDynamicSharedMemorySize, 147456);
    hipFuncSetAttribute(reinterpret_cast<const void*>(gemm2_k),
                        hipFuncAttributeMaxDynamicSharedMemorySize, 147456);

    cvt_x_k   <<<dim3(8192),  dim3(256), 0, stream>>>(x, xb);
    prep_w_k  <<<dim3(1152),  dim3(256), 0, stream>>>(W, b, Wr, br);
    prep_mcs_k<<<dim3(640),   dim3(256), 0, stream>>>(Mc, Ms);
    prep_win_k<<<dim3(4),     dim3(256), 0, stream>>>(wg);
    // GEMM1 (R8-exact path): Sri = epi(xb @ Wr^T), interleaved [32768][1032]
    gemm1_k<<<dim3(1152), dim3(512), 147456, stream>>>(xb, Wr, br, Sri);
    // de-interleave rows in place + extract R512
    deint_k<<<dim3(32768), dim3(256), 0, stream>>>(Sri, R512);
    // GEMM2: e/o half-GEMMs (K=512, A-stride 1032) -> pe/po [32768][520]
    gemm2_k<<<dim3(1280), dim3(512), 147456, stream>>>(Sri, Mc, Ms, pe, po);
    // OLA + fold combine + envelope normalize + trim
    ola_k  <<<dim3(4096), dim3(256), 0, stream>>>(pe, po, R512, wg, out);
    (void)in_sizes; (void)n_in; (void)out_size; (void)ws_size;
}